// Round 7
// baseline (7112.017 us; speedup 1.0000x reference)
//
#include <hip/hip_runtime.h>

// WholeBrainFastDMF: N=360, B=8, T=7500 neural steps (750 hemo).
// One persistent block (1 CU) per batch, 8 waves / 512 threads.
// OCT layout: lane = 8*oc + sl. Oct oc of wave w covers rows 48w+6oc..+5;
// col-slice sl covers cols [48sl,48sl+48) (cols>=360 zero-padded).
// Per lane: sc tile 6 rows x 12 dwords int8 (72 VGPRs), ev read = 3 b128
// (halved vs quad layout -> LDS pipe relief). 3-level DPP butterfly
// (xor1,xor2,row_half_mirror=xor7) reduces each row over the oct; lane sl<6
// updates row 48w+6oc+sl in-register. E int8 double-buffered (linear 384B).
// One lgkm-only barrier per step. Packed-f32 (v_pk_*) update math.

typedef unsigned int u32;
typedef uint4 u32x4;
typedef float f32x2 __attribute__((ext_vector_type(2)));

#define NN 360
#define NB 8
#define NT 7500
#define NHEMO 750

#define S_SC 45720.0f            // sc scale: sc*360 in [0,1) -> *127
#define S_E  64.0f               // E scale (E < 1.98)
#define CONN_K 1.0252653e-7f     // 0.3 / (45720*64)   (G*JN = 0.3 folded)

#if __has_builtin(__builtin_amdgcn_sdot4)
#define DOT4(a,b,c) __builtin_amdgcn_sdot4((a),(b),(c),false)
#elif __has_builtin(__builtin_amdgcn_udot4)
#define DOT4(a,b,c) (int)__builtin_amdgcn_udot4((u32)(a),(u32)(b),(u32)(c),false)
#else
static __device__ __forceinline__ int DOT4(int a, int b, int c) {
  #pragma unroll
  for (int i = 0; i < 4; ++i) c += ((a >> (8*i)) & 0xff) * ((b >> (8*i)) & 0xff);
  return c;
}
#endif

__device__ __forceinline__ float frcp(float x) {
#if __has_builtin(__builtin_amdgcn_rcpf)
  return __builtin_amdgcn_rcpf(x);
#else
  return 1.0f / x;
#endif
}
__device__ __forceinline__ float fexp2(float x) {
#if __has_builtin(__builtin_amdgcn_exp2f)
  return __builtin_amdgcn_exp2f(x);
#else
  return exp2f(x);
#endif
}
__device__ __forceinline__ float flog2(float x) {
#if __has_builtin(__builtin_amdgcn_logf)
  return __builtin_amdgcn_logf(x);
#else
  return log2f(x);
#endif
}

// DPP ctrl: quad_perm xor1 = 0xB1, quad_perm xor2 = 0x4E, row_half_mirror
// (lane^7 within each 8-lane half-row) = 0x141. Basis {1,2,7} spans the oct.
template <int CTRL>
__device__ __forceinline__ int dpp_add_i(int x) {
  return x + __builtin_amdgcn_mov_dpp(x, CTRL, 0xF, 0xF, true);
}
template <int CTRL>
__device__ __forceinline__ float dpp_add_f(float x) {
  return x + __int_as_float(__builtin_amdgcn_mov_dpp(__float_as_int(x), CTRL, 0xF, 0xF, true));
}

// Workgroup barrier WITHOUT vmcnt drain (LDS-visibility only).
__device__ __forceinline__ void lds_barrier() {
  __builtin_amdgcn_sched_barrier(0);
  asm volatile("s_waitcnt lgkmcnt(0)" ::: "memory");
  __builtin_amdgcn_s_barrier();
  asm volatile("" ::: "memory");
  __builtin_amdgcn_sched_barrier(0);
}

__global__ __launch_bounds__(512, 2) void dmf_kernel(
    const float* __restrict__ state,
    const float* __restrict__ noise_in,
    const float* __restrict__ noise_out,
    const float* __restrict__ sc,
    float* __restrict__ out)
{
  const int b   = blockIdx.x;
  const int tid = threadIdx.x;
  const int w   = tid >> 6;
  const int l   = tid & 63;
  const int sl  = l & 7;          // col slice (48 cols)
  const int oc  = l >> 3;         // oct 0..7 (6 rows each)

  const int rbase = 48*w + 6*oc;       // first row of this oct
  const int urow  = rbase + sl;        // row updated by this lane (if upd)
  const bool upd  = (sl < 6) && (urow < NN);
  const int jj    = (sl < 3) ? sl : sl - 3;   // select index within triple

  __shared__ u32 Eq[2][96];       // int8 E, linear 384B (360 data + 24 zero pad)

  if (tid < 192) ((u32*)Eq)[tid] = 0;   // zero both buffers (pads stay 0)

  // ---- load + quantize sc tile: 6 rows x 48 cols -> 72 packed dwords ----
  int scp[6][12];
  float rs[6];
  const int c0 = 48 * sl;
  #pragma unroll
  for (int j = 0; j < 6; ++j) {
    const int gr = rbase + j;
    const bool rvalid = (gr < NN);
    const float* sp = sc + ((size_t)b*NN + (rvalid ? gr : 0))*NN;
    float rsj = 0.f;
    #pragma unroll
    for (int k = 0; k < 12; ++k) {
      int pack = 0;
      #pragma unroll
      for (int e = 0; e < 4; ++e) {
        const int cc = c0 + 4*k + e;
        int q = 0;
        if (rvalid && cc < NN) {
          const float x = sp[cc];
          rsj += x;
          q = (int)rintf(x * S_SC);
        }
        pack |= q << (8*e);
      }
      scp[j][k] = pack;
    }
    rs[j] = rsj;
  }

  // ---- Ji: 3-level DPP oct-reduce of f32 row sums; select mine ----
  #pragma unroll
  for (int j = 0; j < 6; ++j) {
    rs[j] = dpp_add_f<0xB1>(rs[j]);
    rs[j] = dpp_add_f<0x4E>(rs[j]);
    rs[j] = dpp_add_f<0x141>(rs[j]);
  }
  const float mfA = (sl < 3) ? rs[0] : rs[3];
  const float mfB = (sl < 3) ? rs[1] : rs[4];
  const float mfC = (sl < 3) ? rs[2] : rs[5];
  const float rsum = (jj == 0) ? mfA : ((jj == 1) ? mfB : mfC);

  // ---- update-lane init ----
  f32x2 EI = {0.f, 0.f};
  float ss=0.f, ff=0.f, vv=0.f, qq=0.f, Ji=0.f;
  const float* np = noise_in + (size_t)urow * NT * 2 * NB + b;
  f32x2 n0 = {0.f, 0.f}, n1 = {0.f, 0.f};
  __syncthreads();   // Eq zeroing complete (cold path)
  if (upd) {
    Ji = 1.0f + 1.5f * rsum;
    const float* st = state + (size_t)urow * 6 * NB + b;
    EI.x = st[0];
    EI.y = st[NB];
    ss = st[2*NB];
    ff = st[3*NB];
    vv = st[4*NB];
    qq = st[5*NB];
    int q = (int)rintf(EI.x * S_E);
    q = q > 127 ? 127 : q;
    ((char*)&Eq[0][0])[urow] = (char)q;
    n0.x = np[0];      n0.y = np[NB];       // t = 0
    n1.x = np[2*NB];   n1.y = np[3*NB];     // t = 1
  }
  np += 4*NB;        // points at t = 2
  __syncthreads();   // buffer 0 visible

  const u32x4* eq0 = (const u32x4*)&Eq[0][12*sl];
  const u32x4* eq1 = (const u32x4*)&Eq[1][12*sl];
  char* pb0 = (char*)&Eq[0][0] + urow;
  char* pb1 = (char*)&Eq[1][0] + urow;

  // one neural step: read `cur` slice, write byte at `nxt`
  auto body = [&](const u32x4* cur, char* nxt, bool PF, bool hemo) {
    // 1) E slice reads (3 x ds_read_b128)
    const u32x4 e0 = cur[0];
    const u32x4 e1 = cur[1];
    const u32x4 e2 = cur[2];

    // 2) noise prefetch t+2 (stays in flight across lgkm-only barriers)
    f32x2 n2 = n1;
    if (PF) {
      if (upd) { n2.x = np[0]; n2.y = np[NB]; }
      np += 2*NB;
    }

    // 3) dots: 6 rows x 48 cols
    int a0=0, a1=0, a2=0, a3=0, a4=0, a5=0;
    #pragma unroll
    for (int q4 = 0; q4 < 4; ++q4) {
      const int ex = (q4==0) ? (int)e0.x : (q4==1) ? (int)e0.y : (q4==2) ? (int)e0.z : (int)e0.w;
      a0 = DOT4(scp[0][q4], ex, a0);
      a1 = DOT4(scp[1][q4], ex, a1);
      a2 = DOT4(scp[2][q4], ex, a2);
      a3 = DOT4(scp[3][q4], ex, a3);
      a4 = DOT4(scp[4][q4], ex, a4);
      a5 = DOT4(scp[5][q4], ex, a5);
    }
    #pragma unroll
    for (int q4 = 0; q4 < 4; ++q4) {
      const int ex = (q4==0) ? (int)e1.x : (q4==1) ? (int)e1.y : (q4==2) ? (int)e1.z : (int)e1.w;
      a0 = DOT4(scp[0][4+q4], ex, a0);
      a1 = DOT4(scp[1][4+q4], ex, a1);
      a2 = DOT4(scp[2][4+q4], ex, a2);
      a3 = DOT4(scp[3][4+q4], ex, a3);
      a4 = DOT4(scp[4][4+q4], ex, a4);
      a5 = DOT4(scp[5][4+q4], ex, a5);
    }
    #pragma unroll
    for (int q4 = 0; q4 < 4; ++q4) {
      const int ex = (q4==0) ? (int)e2.x : (q4==1) ? (int)e2.y : (q4==2) ? (int)e2.z : (int)e2.w;
      a0 = DOT4(scp[0][8+q4], ex, a0);
      a1 = DOT4(scp[1][8+q4], ex, a1);
      a2 = DOT4(scp[2][8+q4], ex, a2);
      a3 = DOT4(scp[3][8+q4], ex, a3);
      a4 = DOT4(scp[4][8+q4], ex, a4);
      a5 = DOT4(scp[5][8+q4], ex, a5);
    }
    // oct butterfly: every lane gets all six row sums
    a0 = dpp_add_i<0xB1>(a0); a0 = dpp_add_i<0x4E>(a0); a0 = dpp_add_i<0x141>(a0);
    a1 = dpp_add_i<0xB1>(a1); a1 = dpp_add_i<0x4E>(a1); a1 = dpp_add_i<0x141>(a1);
    a2 = dpp_add_i<0xB1>(a2); a2 = dpp_add_i<0x4E>(a2); a2 = dpp_add_i<0x141>(a2);
    a3 = dpp_add_i<0xB1>(a3); a3 = dpp_add_i<0x4E>(a3); a3 = dpp_add_i<0x141>(a3);
    a4 = dpp_add_i<0xB1>(a4); a4 = dpp_add_i<0x4E>(a4); a4 = dpp_add_i<0x141>(a4);
    a5 = dpp_add_i<0xB1>(a5); a5 = dpp_add_i<0x4E>(a5); a5 = dpp_add_i<0x141>(a5);
    const int mA = (sl < 3) ? a0 : a3;
    const int mB = (sl < 3) ? a1 : a4;
    const int mC = (sl < 3) ? a2 : a5;
    const int ci = (jj == 0) ? mA : ((jj == 1) ? mB : mC);

    if (upd) {
      const float conn = (float)ci * CONN_K;               // G*JN*conn
      f32x2 P;
      P.x = 0.382f + 0.21f*EI.x + conn - Ji*EI.y;
      P.y = 0.2674f + 0.15f*EI.x - EI.y;
      P = P > (f32x2){0.f, 0.f} ? P : (f32x2){0.f, 0.f};   // relu (pk_max)
      f32x2 X = P * (f32x2){310.f, 615.f} + (f32x2){-125.f, -177.f};
      f32x2 Ax = X * (f32x2){-0.23083120f, -0.12551447f};  // -d*x * log2(e)
      f32x2 Ex = {fexp2(Ax.x), fexp2(Ax.y)};
      f32x2 Dn = (f32x2){1.00000001f, 1.00000001f} - Ex;
      f32x2 Rr = X * (f32x2){frcp(Dn.x), frcp(Dn.y)};
      f32x2 Gg = {(1.f - EI.x) * 0.000641f, 0.001f};
      f32x2 Dd = Gg * Rr + EI * (f32x2){-0.01f, -0.1f};
      EI = EI + Dd * (f32x2){0.1f, 0.1f} + n0 * (f32x2){0.00158113883f, 0.00158113883f};
      EI = EI > (f32x2){0.f, 0.f} ? EI : (f32x2){0.f, 0.f};
      int q = (int)(EI.x * S_E + 0.5f);
      q = q > 127 ? 127 : q;
      *nxt = (char)q;
      if (hemo) {
        const float l2v  = flog2(vv);
        const float v_ia = fexp2(3.125f * l2v);            // v**(1/0.32)
        const float v_r  = fexp2(2.125f * l2v);            // v**(1/0.32-1)
        const float ds_  = EI.x - 1.53846153846f*ss - 2.43902439024f*(ff - 1.f);
        const float df_  = ss;
        const float dv_  = (ff - v_ia) * 1.02040816327f;
        const float pw   = fexp2(-0.59946207f * frcp(ff)); // (1-RHO)**(1/f)
        const float dq_  = (ff*2.94117647059f*(1.f - pw) - qq*v_r) * 1.02040816327f;
        ss += 1e-3f*ds_;
        ff += 1e-3f*df_;
        vv += 1e-3f*dv_;
        qq += 1e-3f*dq_;
      }
    }
    n0 = n1; n1 = n2;
    lds_barrier();   // next buffer complete; vmcnt loads stay in flight
  };

  for (int hs = 0; hs < NHEMO; ++hs) {
    body(eq0, pb1, true, false);
    body(eq1, pb0, true, false);
    body(eq0, pb1, true, false);
    body(eq1, pb0, true, false);
    body(eq0, pb1, true, false);
    body(eq1, pb0, true, false);
    body(eq0, pb1, true, false);
    body(eq1, pb0, true, false);
    if (hs != NHEMO - 1) {
      body(eq0, pb1, true, false);
      body(eq1, pb0, true, true);
    } else {
      body(eq0, pb1, false, false);
      body(eq1, pb0, false, true);
    }
  }

  // ---- outputs: next_state (N,6,B) then bold (N,B) ----
  if (upd) {
    float* o = out + (size_t)urow * 6 * NB + b;
    o[0]    = EI.x;
    o[NB]   = EI.y;
    o[2*NB] = ss;
    o[3*NB] = ff;
    o[4*NB] = vv;
    o[5*NB] = qq;
    out[NN*6*NB + urow*NB + b] =
        20.f*(2.38f*(1.f - qq) + 2.f*(1.f - qq/vv) + 0.48f*(1.f - vv))
        + noise_out[urow*NB + b];
  }
}

extern "C" void kernel_launch(void* const* d_in, const int* in_sizes, int n_in,
                              void* d_out, int out_size, void* d_ws, size_t ws_size,
                              hipStream_t stream) {
  const float* state     = (const float*)d_in[0];
  // d_in[1] = delays (unused by the reference simulation)
  const float* noise_in  = (const float*)d_in[2];
  const float* noise_out = (const float*)d_in[3];
  const float* sc        = (const float*)d_in[4];
  float* out = (float*)d_out;
  dmf_kernel<<<NB, 512, 0, stream>>>(state, noise_in, noise_out, sc, out);
}

// Round 8
// 4388.436 us; speedup vs baseline: 1.6206x; 1.6206x over previous
//
#include <hip/hip_runtime.h>

// WholeBrainFastDMF: N=360, B=8, T=7500 neural steps (750 hemo).
// One persistent block (1 CU) per batch, 8 waves / 512 threads.
// MATVEC ON THE MFMA PIPE: conn = sc_q(int8) . E_q(int8) via
// v_mfma_i32_16x16x64_i8, with E broadcast across all 16 B-columns so every
// column of C equals y -> lane (g<<4|c) holds y[16T+4g+reg] in its own acc
// regs (C layout: col=lane&15, row=(lane>>4)*4+reg). No butterfly, no
// handoff. Wave w owns rows [48w,48w+48) as 3 row-tiles of 16.
// A-frags: 3 tiles x 6 kfrags x 4 VGPRs = 72 (int8, k-slices per lane-group).
// E int8 double-buffered in LDS (linear 384B, zero pad 360..383).
// One lgkm-only barrier per step; 2-step noise prefetch; fast rcp/exp2/log2.

typedef unsigned int u32;
typedef int i32x4 __attribute__((ext_vector_type(4)));

#define NN 360
#define NB 8
#define NT 7500
#define NHEMO 750

#define S_SC 45720.0f            // sc scale: sc*360 in [0,1) -> *127
#define S_E  64.0f               // E scale (E < 1.98)
#define CONN_K 1.0252653e-7f     // 0.3 / (45720*64)   (G*JN = 0.3 folded)

__device__ __forceinline__ float frcp(float x) {
#if __has_builtin(__builtin_amdgcn_rcpf)
  return __builtin_amdgcn_rcpf(x);
#else
  return 1.0f / x;
#endif
}
__device__ __forceinline__ float fexp2(float x) {
#if __has_builtin(__builtin_amdgcn_exp2f)
  return __builtin_amdgcn_exp2f(x);
#else
  return exp2f(x);
#endif
}
__device__ __forceinline__ float flog2(float x) {
#if __has_builtin(__builtin_amdgcn_logf)
  return __builtin_amdgcn_logf(x);
#else
  return log2f(x);
#endif
}

// Workgroup barrier WITHOUT vmcnt drain (LDS-visibility only).
__device__ __forceinline__ void lds_barrier() {
  __builtin_amdgcn_sched_barrier(0);
  asm volatile("s_waitcnt lgkmcnt(0)" ::: "memory");
  __builtin_amdgcn_s_barrier();
  asm volatile("" ::: "memory");
  __builtin_amdgcn_sched_barrier(0);
}

__global__ __launch_bounds__(512, 2) void dmf_kernel(
    const float* __restrict__ state,
    const float* __restrict__ noise_in,
    const float* __restrict__ noise_out,
    const float* __restrict__ sc,
    float* __restrict__ out)
{
  const int b   = blockIdx.x;
  const int tid = threadIdx.x;
  const int w   = tid >> 6;
  const int l   = tid & 63;
  const int g   = l >> 4;        // k-slice group (A/B) AND C row-group
  const int r   = l & 15;        // A row within tile; also C col index c
  // owner decode: lane (g<<4)|c with c<12 owns row 48w + 16*(c>>2) + 4g + (c&3)
  const int t_o = r >> 2;        // owner tile 0..3 (valid < 3)
  const int j_o = r & 3;         // acc register index
  const int R_o = 48*w + 16*t_o + 4*g + j_o;
  const bool upd = (r < 12) && (R_o < NN);
  const int Rn  = upd ? R_o : 0; // safe row for address bases

  __shared__ u32 xq[2][96];      // int8 E, linear 384B each (360 data + 24 zero)

  if (tid < 192) ((u32*)xq)[tid] = 0;   // zero both buffers (pads stay 0)

  // ---- build A-frags: quantize sc rows into MFMA layout; f32 row sums ----
  // lane supplies row (48w+16t + r), k-bytes 64*kf + 16*g + 0..15
  i32x4 afr[3][6];
  float rs[3];
  #pragma unroll
  for (int t = 0; t < 3; ++t) {
    const int R = 48*w + 16*t + r;
    const bool rv = (R < NN);
    const float* sp = sc + ((size_t)b*NN + (rv ? R : 0))*NN;
    float acc = 0.f;
    #pragma unroll
    for (int kf = 0; kf < 6; ++kf) {
      i32x4 pk;
      #pragma unroll
      for (int d = 0; d < 4; ++d) {
        int packv = 0;
        #pragma unroll
        for (int e = 0; e < 4; ++e) {
          const int k = 64*kf + 16*g + 4*d + e;
          int q = 0;
          if (rv && k < NN) {
            const float x = sp[k];
            acc += x;
            q = (int)rintf(x * S_SC);
          }
          packv |= q << (8*e);
        }
        pk[d] = packv;
      }
      afr[t][kf] = pk;
    }
    rs[t] = acc;
  }
  // full row sums: reduce over the 4 k-slice groups (lanes ^16, ^32)
  #pragma unroll
  for (int t = 0; t < 3; ++t) {
    rs[t] += __shfl_xor(rs[t], 16, 64);
    rs[t] += __shfl_xor(rs[t], 32, 64);
  }
  // owner pulls rowsum of in-tile row rho = 4g + j_o (held by lane rho, tile t_o)
  const int rho = 4*g + j_o;
  const int qs0 = __builtin_amdgcn_ds_bpermute(4*rho, __float_as_int(rs[0]));
  const int qs1 = __builtin_amdgcn_ds_bpermute(4*rho, __float_as_int(rs[1]));
  const int qs2 = __builtin_amdgcn_ds_bpermute(4*rho, __float_as_int(rs[2]));
  const float rsum = __int_as_float((t_o == 0) ? qs0 : ((t_o == 1) ? qs1 : qs2));

  // ---- owner init: Ji, state, publish E into buffer 0, noise t=0,1 ----
  float E=0.f, I=0.f, ss=0.f, ff=0.f, vv=0.f, qq=0.f, Ji=0.f;
  const float* np = noise_in + (size_t)Rn * NT * 2 * NB + b;
  float n0E=0.f, n0I=0.f, n1E=0.f, n1I=0.f;
  __syncthreads();   // xq zeroing complete
  if (upd) {
    Ji = 1.0f + 1.5f * rsum;
    const float* st = state + (size_t)R_o * 6 * NB + b;
    E  = st[0];
    I  = st[NB];
    ss = st[2*NB];
    ff = st[3*NB];
    vv = st[4*NB];
    qq = st[5*NB];
    int qv = (int)rintf(E * S_E);
    qv = qv > 127 ? 127 : qv;
    ((char*)&xq[0][0])[R_o] = (char)qv;
    n0E = np[0];      n0I = np[NB];       // t = 0
    n1E = np[2*NB];   n1I = np[3*NB];     // t = 1
  }
  np += 4*NB;        // points at t = 2
  __syncthreads();   // buffer 0 visible

  const u32* xb0 = &xq[0][4*g];
  const u32* xb1 = &xq[1][4*g];
  char* pb0 = (char*)&xq[0][0] + Rn;
  char* pb1 = (char*)&xq[1][0] + Rn;
  const bool w7 = (w == 7);      // wave 7 tile 2 = rows 368..383, all zero

  // one neural step: read B-frags from xb, write E byte at pbn
  auto body = [&](const u32* xb, char* pbn, bool PF, bool hemo) {
    // 1) B-frags: x k-slice per group g, same for all tiles (6 x ds_read_b128)
    i32x4 bf[6];
    #pragma unroll
    for (int kf = 0; kf < 6; ++kf) bf[kf] = *(const i32x4*)(xb + 16*kf);

    // 2) noise prefetch t+2 (stays in flight across lgkm-only barriers)
    float n2E = n1E, n2I = n1I;
    if (PF) {
      if (upd) { n2E = np[0]; n2I = np[NB]; }
      np += 2*NB;
    }

    // 3) matvec on the MFMA pipe: 3 accumulate chains of 6
    i32x4 ac0 = {0,0,0,0}, ac1 = {0,0,0,0}, ac2 = {0,0,0,0};
    #pragma unroll
    for (int kf = 0; kf < 6; ++kf)
      ac0 = __builtin_amdgcn_mfma_i32_16x16x64_i8(afr[0][kf], bf[kf], ac0, 0, 0, 0);
    #pragma unroll
    for (int kf = 0; kf < 6; ++kf)
      ac1 = __builtin_amdgcn_mfma_i32_16x16x64_i8(afr[1][kf], bf[kf], ac1, 0, 0, 0);
    if (!w7) {
      #pragma unroll
      for (int kf = 0; kf < 6; ++kf)
        ac2 = __builtin_amdgcn_mfma_i32_16x16x64_i8(afr[2][kf], bf[kf], ac2, 0, 0, 0);
    }

    // 4) conn: every B-column equals y, so my acc reg j_o of tile t_o IS y[R_o]
    const i32x4 at = (t_o == 0) ? ac0 : ((t_o == 1) ? ac1 : ac2);
    const int ci = (j_o == 0) ? at.x : ((j_o == 1) ? at.y : ((j_o == 2) ? at.z : at.w));

    if (upd) {
      const float cs = (float)ci * CONN_K;                 // G*JN*conn
      float I_E = fmaxf(0.382f + 0.21f*E + cs - Ji*I, 0.f);
      float I_I = fmaxf(0.2674f + 0.15f*E - I, 0.f);
      const float xE  = 310.f*I_E - 125.f;
      const float R_E = xE * frcp(1.f - fexp2(-0.23083120f*xE) + 1e-8f);
      const float xI  = 615.f*I_I - 177.f;
      const float R_I = xI * frcp(1.f - fexp2(-0.12551447f*xI) + 1e-8f);
      const float dE = -E*0.01f + (1.f - E)*0.000641f*R_E;
      const float dI = -I*0.1f  + 0.001f*R_I;
      E = fmaxf(E + 0.1f*dE + 0.00158113883f*n0E, 0.f);
      I = fmaxf(I + 0.1f*dI + 0.00158113883f*n0I, 0.f);
      int qv = (int)(E * S_E + 0.5f);
      qv = qv > 127 ? 127 : qv;
      *pbn = (char)qv;
      if (hemo) {
        const float l2v  = flog2(vv);
        const float v_ia = fexp2(3.125f * l2v);            // v**(1/0.32)
        const float v_r  = fexp2(2.125f * l2v);            // v**(1/0.32-1)
        const float ds_  = E - 1.53846153846f*ss - 2.43902439024f*(ff - 1.f);
        const float df_  = ss;
        const float dv_  = (ff - v_ia) * 1.02040816327f;
        const float pw   = fexp2(-0.59946207f * frcp(ff)); // (1-RHO)**(1/f)
        const float dq_  = (ff*2.94117647059f*(1.f - pw) - qq*v_r) * 1.02040816327f;
        ss += 1e-3f*ds_;
        ff += 1e-3f*df_;
        vv += 1e-3f*dv_;
        qq += 1e-3f*dq_;
      }
    }
    n0E = n1E; n0I = n1I;
    n1E = n2E; n1I = n2I;
    lds_barrier();   // next buffer complete; vmcnt loads stay in flight
  };

  for (int hs = 0; hs < NHEMO; ++hs) {
    body(xb0, pb1, true, false);
    body(xb1, pb0, true, false);
    body(xb0, pb1, true, false);
    body(xb1, pb0, true, false);
    body(xb0, pb1, true, false);
    body(xb1, pb0, true, false);
    body(xb0, pb1, true, false);
    body(xb1, pb0, true, false);
    if (hs != NHEMO - 1) {
      body(xb0, pb1, true, false);
      body(xb1, pb0, true, true);
    } else {
      body(xb0, pb1, false, false);
      body(xb1, pb0, false, true);
    }
  }

  // ---- outputs: next_state (N,6,B) then bold (N,B) ----
  if (upd) {
    float* o = out + (size_t)R_o * 6 * NB + b;
    o[0]    = E;
    o[NB]   = I;
    o[2*NB] = ss;
    o[3*NB] = ff;
    o[4*NB] = vv;
    o[5*NB] = qq;
    out[NN*6*NB + R_o*NB + b] =
        20.f*(2.38f*(1.f - qq) + 2.f*(1.f - qq/vv) + 0.48f*(1.f - vv))
        + noise_out[R_o*NB + b];
  }
}

extern "C" void kernel_launch(void* const* d_in, const int* in_sizes, int n_in,
                              void* d_out, int out_size, void* d_ws, size_t ws_size,
                              hipStream_t stream) {
  const float* state     = (const float*)d_in[0];
  // d_in[1] = delays (unused by the reference simulation)
  const float* noise_in  = (const float*)d_in[2];
  const float* noise_out = (const float*)d_in[3];
  const float* sc        = (const float*)d_in[4];
  float* out = (float*)d_out;
  dmf_kernel<<<NB, 512, 0, stream>>>(state, noise_in, noise_out, sc, out);
}